// Round 1
// baseline (1302.645 us; speedup 1.0000x reference)
//
#include <hip/hip_runtime.h>

#define S_LEN 2048
#define DHEAD 64
#define DPOS  32
#define PITCH 104              // f16 elems per LDS row (96 padded -> 104; 2-way bank alias = free)
#define BM    128              // q rows per workgroup
#define BN    64               // k rows per tile
#define NKT   (S_LEN / BN)     // 32
#define NQT   (S_LEN / BM)     // 16

using f16   = _Float16;
using f16x4 = __attribute__((ext_vector_type(4))) _Float16;
using f16x8 = __attribute__((ext_vector_type(8))) _Float16;
using f32x4 = __attribute__((ext_vector_type(4))) float;

__device__ __forceinline__ f16 clamp_cvt(float x, float s) {
    return (f16)(fminf(fmaxf(x, -5.0f), 5.0f) * s);
}

__global__ __launch_bounds__(256, 4)
void attn_map_kernel(const float* __restrict__ keys,
                     const float* __restrict__ queries,
                     const float* __restrict__ pos_key,
                     const float* __restrict__ pos_query,
                     float* __restrict__ out) {
    __shared__ f16 q_lds[BM * PITCH];   // 26624 B
    __shared__ f16 k_lds[BN * PITCH];   // 13312 B

    const int tid  = threadIdx.x;
    const int wave = tid >> 6;
    const int lane = tid & 63;
    const int quad = lane >> 4;
    const int mcol = lane & 15;

    const int bid = blockIdx.x;
    const int bh  = bid >> 4;          // 64 heads, NQT=16 tiles each
    const int qt  = bid & (NQT - 1);
    const int q0  = qt * BM;

    const float* gq  = queries   + (size_t)bh * S_LEN * DHEAD;
    const float* gk  = keys      + (size_t)bh * S_LEN * DHEAD;
    const float* gpq = pos_query + (size_t)bh * S_LEN * DPOS;
    const float* gpk = pos_key   + (size_t)bh * S_LEN * DPOS;
    float*       go  = out       + (size_t)bh * S_LEN * S_LEN;

    const float scl  = 0.125f;                  // 1/sqrt(64)
    const float rscl = 0.17677669529663689f;    // 1/sqrt(32)

    // ---- stage Q tile (pre-scaled) + PQ tile into q_lds (f16) ----
    #pragma unroll
    for (int i = 0; i < 8; ++i) {               // 128 rows * 16 float4
        int idx = tid + i * 256;
        int r = idx >> 4, c = idx & 15;
        float4 v = *(const float4*)(gq + (size_t)(q0 + r) * DHEAD + c * 4);
        f16x4 h = { clamp_cvt(v.x, scl), clamp_cvt(v.y, scl),
                    clamp_cvt(v.z, scl), clamp_cvt(v.w, scl) };
        *(f16x4*)(q_lds + r * PITCH + c * 4) = h;
    }
    #pragma unroll
    for (int i = 0; i < 4; ++i) {               // 128 rows * 8 float4
        int idx = tid + i * 256;
        int r = idx >> 3, c = idx & 7;
        float4 v = *(const float4*)(gpq + (size_t)(q0 + r) * DPOS + c * 4);
        f16x4 h = { clamp_cvt(v.x, rscl), clamp_cvt(v.y, rscl),
                    clamp_cvt(v.z, rscl), clamp_cvt(v.w, rscl) };
        *(f16x4*)(q_lds + r * PITCH + 64 + c * 4) = h;
    }
    __syncthreads();

    // ---- A fragments: wave owns rows wave*32 .. wave*32+31 (2 row-blocks) ----
    f16x8 afrag[2][3];
    #pragma unroll
    for (int rb = 0; rb < 2; ++rb) {
        int row = wave * 32 + rb * 16 + mcol;
        #pragma unroll
        for (int t = 0; t < 3; ++t)
            afrag[rb][t] = *(const f16x8*)(q_lds + row * PITCH + t * 32 + quad * 8);
    }

    auto stage_k = [&](int kt) {
        const int k0 = kt * BN;
        #pragma unroll
        for (int i = 0; i < 4; ++i) {           // 64 rows * 16 float4
            int idx = tid + i * 256;
            int r = idx >> 4, c = idx & 15;
            float4 v = *(const float4*)(gk + (size_t)(k0 + r) * DHEAD + c * 4);
            f16x4 h = { clamp_cvt(v.x, 1.f), clamp_cvt(v.y, 1.f),
                        clamp_cvt(v.z, 1.f), clamp_cvt(v.w, 1.f) };
            *(f16x4*)(k_lds + r * PITCH + c * 4) = h;
        }
        #pragma unroll
        for (int i = 0; i < 2; ++i) {           // 64 rows * 8 float4
            int idx = tid + i * 256;
            int r = idx >> 3, c = idx & 7;
            float4 v = *(const float4*)(gpk + (size_t)(k0 + r) * DPOS + c * 4);
            f16x4 h = { clamp_cvt(v.x, 1.f), clamp_cvt(v.y, 1.f),
                        clamp_cvt(v.z, 1.f), clamp_cvt(v.w, 1.f) };
            *(f16x4*)(k_lds + r * PITCH + 64 + c * 4) = h;
        }
    };

    // ---- pass 1: per-lane online max/sum over this lane's columns ----
    float m_run[2][4], l_run[2][4];
    #pragma unroll
    for (int rb = 0; rb < 2; ++rb)
        #pragma unroll
        for (int r = 0; r < 4; ++r) { m_run[rb][r] = -1e30f; l_run[rb][r] = 0.0f; }

    for (int kt = 0; kt < NKT; ++kt) {
        stage_k(kt);
        __syncthreads();

        f32x4 c[2][4];
        #pragma unroll
        for (int cb = 0; cb < 4; ++cb) {
            const f16* kb = k_lds + (cb * 16 + mcol) * PITCH + quad * 8;
            f16x8 b0 = *(const f16x8*)(kb);
            f16x8 b1 = *(const f16x8*)(kb + 32);
            f16x8 b2 = *(const f16x8*)(kb + 64);
            #pragma unroll
            for (int rb = 0; rb < 2; ++rb) {
                f32x4 acc = {0.f, 0.f, 0.f, 0.f};
                acc = __builtin_amdgcn_mfma_f32_16x16x32_f16(afrag[rb][0], b0, acc, 0, 0, 0);
                acc = __builtin_amdgcn_mfma_f32_16x16x32_f16(afrag[rb][1], b1, acc, 0, 0, 0);
                acc = __builtin_amdgcn_mfma_f32_16x16x32_f16(afrag[rb][2], b2, acc, 0, 0, 0);
                c[rb][cb] = acc;
            }
        }

        #pragma unroll
        for (int rb = 0; rb < 2; ++rb) {
            #pragma unroll
            for (int r = 0; r < 4; ++r) {
                float v0 = c[rb][0][r], v1 = c[rb][1][r], v2 = c[rb][2][r], v3 = c[rb][3][r];
                float tm = fmaxf(fmaxf(v0, v1), fmaxf(v2, v3));
                float m  = m_run[rb][r];
                float nm = fmaxf(m, tm);
                float ts = __expf(v0 - nm) + __expf(v1 - nm) + __expf(v2 - nm) + __expf(v3 - nm);
                l_run[rb][r] = l_run[rb][r] * __expf(m - nm) + ts;
                m_run[rb][r] = nm;
            }
        }
        __syncthreads();
    }

    // ---- merge (m,l) across the 16 lanes of each quad; store 1/l in l_run ----
    #pragma unroll
    for (int rb = 0; rb < 2; ++rb) {
        #pragma unroll
        for (int r = 0; r < 4; ++r) {
            float m = m_run[rb][r], l = l_run[rb][r];
            #pragma unroll
            for (int off = 1; off < 16; off <<= 1) {
                float om = __shfl_xor(m, off);
                float ol = __shfl_xor(l, off);
                float nm = fmaxf(m, om);
                l = l * __expf(m - nm) + ol * __expf(om - nm);
                m = nm;
            }
            m_run[rb][r] = m;
            l_run[rb][r] = 1.0f / l;
        }
    }

    // ---- pass 2: recompute scores, write normalized probabilities ----
    for (int kt = 0; kt < NKT; ++kt) {
        stage_k(kt);
        __syncthreads();

        #pragma unroll
        for (int cb = 0; cb < 4; ++cb) {
            const f16* kb = k_lds + (cb * 16 + mcol) * PITCH + quad * 8;
            f16x8 b0 = *(const f16x8*)(kb);
            f16x8 b1 = *(const f16x8*)(kb + 32);
            f16x8 b2 = *(const f16x8*)(kb + 64);
            #pragma unroll
            for (int rb = 0; rb < 2; ++rb) {
                f32x4 acc = {0.f, 0.f, 0.f, 0.f};
                acc = __builtin_amdgcn_mfma_f32_16x16x32_f16(afrag[rb][0], b0, acc, 0, 0, 0);
                acc = __builtin_amdgcn_mfma_f32_16x16x32_f16(afrag[rb][1], b1, acc, 0, 0, 0);
                acc = __builtin_amdgcn_mfma_f32_16x16x32_f16(afrag[rb][2], b2, acc, 0, 0, 0);

                const int row0 = q0 + wave * 32 + rb * 16 + quad * 4;
                const int col  = kt * BN + cb * 16 + mcol;
                float* op = go + (size_t)row0 * S_LEN + col;
                #pragma unroll
                for (int r = 0; r < 4; ++r) {
                    float p = __expf(acc[r] - m_run[rb][r]) * l_run[rb][r];
                    op[(size_t)r * S_LEN] = p;
                }
            }
        }
        __syncthreads();
    }
}

extern "C" void kernel_launch(void* const* d_in, const int* in_sizes, int n_in,
                              void* d_out, int out_size, void* d_ws, size_t ws_size,
                              hipStream_t stream) {
    const float* keys      = (const float*)d_in[0];
    const float* queries   = (const float*)d_in[1];
    const float* pos_key   = (const float*)d_in[2];
    const float* pos_query = (const float*)d_in[3];
    float* out = (float*)d_out;

    dim3 grid(64 * NQT);   // 64 (b*h) * 16 q-tiles = 1024 blocks
    dim3 block(256);
    attn_map_kernel<<<grid, block, 0, stream>>>(keys, queries, pos_key, pos_query, out);
}